// Round 1
// baseline (666.462 us; speedup 1.0000x reference)
//
#include <hip/hip_runtime.h>
#include <math.h>

#define IN_SIZE 128
#define E_SIZE  32
#define KDIM    160
#define THRESH  0.5f
#define CAP     128   // max edges cached in LDS per node (max degree ~60 expected)

// ---------------- CSR construction ----------------

__global__ void k_hist(const int* __restrict__ dst, int* __restrict__ deg, int E) {
    int i = blockIdx.x * blockDim.x + threadIdx.x;
    if (i < E) atomicAdd(&deg[dst[i]], 1);
}

__global__ void k_blocksum(const int* __restrict__ deg, int* __restrict__ bsum, int N) {
    __shared__ int s[512];
    int i = blockIdx.x * 512 + threadIdx.x;
    s[threadIdx.x] = (i < N) ? deg[i] : 0;
    __syncthreads();
    for (int off = 256; off > 0; off >>= 1) {
        if (threadIdx.x < off) s[threadIdx.x] += s[threadIdx.x + off];
        __syncthreads();
    }
    if (threadIdx.x == 0) bsum[blockIdx.x] = s[0];
}

__global__ void k_scanbsum(const int* __restrict__ bsum, int* __restrict__ bscan,
                           int nb, int* __restrict__ offsets, int N) {
    if (blockIdx.x == 0 && threadIdx.x == 0) {
        int run = 0;
        for (int b = 0; b < nb; ++b) { bscan[b] = run; run += bsum[b]; }
        offsets[N] = run;   // == E
    }
}

__global__ void k_offsets(const int* __restrict__ deg, const int* __restrict__ bscan,
                          int* __restrict__ offsets, int* __restrict__ cursor, int N) {
    __shared__ int s[512];
    int tid = threadIdx.x;
    int i = blockIdx.x * 512 + tid;
    int v = (i < N) ? deg[i] : 0;
    s[tid] = v;
    __syncthreads();
    for (int off = 1; off < 512; off <<= 1) {       // Hillis-Steele inclusive scan
        int add = (tid >= off) ? s[tid - off] : 0;
        __syncthreads();
        s[tid] += add;
        __syncthreads();
    }
    if (i < N) {
        int o = bscan[blockIdx.x] + s[tid] - v;     // exclusive
        offsets[i] = o;
        cursor[i]  = o;
    }
}

__global__ void k_fill(const int* __restrict__ dst, int* __restrict__ cursor,
                       int* __restrict__ eids, int E) {
    int i = blockIdx.x * blockDim.x + threadIdx.x;
    if (i < E) {
        int p = atomicAdd(&cursor[dst[i]], 1);
        eids[p] = i;
    }
}

// ---------------- per-node aggregate (1 wave / node) ----------------
// lanes (half, j): half = lane>>5 handles edges i with i%2==half, j = lane&31 owns feature j.

#define HALF_RED(x) { x += __shfl_xor(x, 1); x += __shfl_xor(x, 2); x += __shfl_xor(x, 4); \
                      x += __shfl_xor(x, 8); x += __shfl_xor(x, 16); }

__global__ __launch_bounds__(64) void k_node(
    const float* __restrict__ ef, const int* __restrict__ offsets,
    const int* __restrict__ eids, float* __restrict__ agg, int N)
{
    __shared__ float cache[CAP][E_SIZE];   // 16 KB
    int n = blockIdx.x;
    int lane = threadIdx.x;
    int half = lane >> 5;
    int j = lane & 31;
    int start = offsets[n];
    int deg = offsets[n + 1] - start;

    // phase A: sum of edge features; stage rows in LDS
    float esum = 0.f;
    for (int i = half; i < deg; i += 2) {
        int eid = eids[start + i];
        float f = ef[(size_t)eid * E_SIZE + j];
        if (i < CAP) cache[i][j] = f;
        esum += f;
    }
    esum += __shfl_xor(esum, 32);                       // combine halves
    float hk = (deg > 0) ? esum / (float)deg : 0.f;     // lane holds hk[j]
    float hn2 = hk * hk;
    HALF_RED(hn2);                                      // ||hk||^2 (full, per half)
    float hnorm = sqrtf(hn2);

    // phase B: cosine mask + masked sums (edge rows from LDS)
    float ssum = 0.f, scnt = 0.f;
    for (int i = half; i < deg; i += 2) {
        float f = (i < CAP) ? cache[i][j]
                            : ef[(size_t)eids[start + i] * E_SIZE + j];
        float num = hk * f;
        float fn2 = f * f;
        HALF_RED(num);
        HALF_RED(fn2);
        float cosv = num / (hnorm * sqrtf(fn2));        // NaN (0/0) -> mask false, matches jnp
        if (cosv < THRESH) { ssum += f; scnt += 1.f; }
    }
    ssum += __shfl_xor(ssum, 32);
    scnt += __shfl_xor(scnt, 32);

    float a = (scnt > 0.f) ? ssum / scnt : hk;
    if (half == 0) agg[(size_t)n * E_SIZE + j] = a;
}

// ---------------- GEMM: out[N][128] = [h_in | agg] @ W^T ----------------
// BM=128, BN=128(all), BK=32; 256 threads; 8x8 acc per thread.

__global__ __launch_bounds__(256) void k_gemm(
    const float* __restrict__ A0,   // h_in [N][128]
    const float* __restrict__ A1,   // agg  [N][32]
    const float* __restrict__ W,    // [128][160]
    float* __restrict__ out, int N)
{
    __shared__ float As[128][33];   // +1 pad: a-reads conflict-free
    __shared__ float Bs[32][132];   // transposed W chunk; 132 keeps float4 rows 16B-aligned
    int t = threadIdx.x;
    int m0 = blockIdx.x * 128;
    int tn = t & 15, tm = t >> 4;
    float acc[8][8];
    #pragma unroll
    for (int r = 0; r < 8; ++r)
        #pragma unroll
        for (int c = 0; c < 8; ++c) acc[r][c] = 0.f;

    for (int chunk = 0; chunk < 5; ++chunk) {
        // stage A tile (rows m0..m0+127, k-cols chunk*32..+31)
        #pragma unroll
        for (int l = 0; l < 4; ++l) {
            int id = l * 256 + t;          // 0..1023 float4 slots
            int r = id >> 3;               // 0..127
            int q = id & 7;                // float4 col within 32
            int m = m0 + r;
            float4 v = make_float4(0.f, 0.f, 0.f, 0.f);
            if (m < N) {
                if (chunk < 4) v = *(const float4*)&A0[(size_t)m * IN_SIZE + chunk * 32 + q * 4];
                else           v = *(const float4*)&A1[(size_t)m * E_SIZE + q * 4];
            }
            As[r][q * 4 + 0] = v.x; As[r][q * 4 + 1] = v.y;
            As[r][q * 4 + 2] = v.z; As[r][q * 4 + 3] = v.w;
        }
        // stage W chunk transposed: Bs[kk][h] = W[h][chunk*32+kk]
        {
            int h  = t >> 1;
            int kb = (t & 1) * 16;
            #pragma unroll
            for (int i2 = 0; i2 < 4; ++i2) {
                float4 v = *(const float4*)&W[(size_t)h * KDIM + chunk * 32 + kb + i2 * 4];
                int kkq = kb + i2 * 4;
                Bs[kkq + 0][h] = v.x; Bs[kkq + 1][h] = v.y;
                Bs[kkq + 2][h] = v.z; Bs[kkq + 3][h] = v.w;
            }
        }
        __syncthreads();
        #pragma unroll 4
        for (int kk = 0; kk < 32; ++kk) {
            float a[8], b[8];
            #pragma unroll
            for (int r = 0; r < 8; ++r) a[r] = As[tm * 8 + r][kk];
            float4 b0 = *(const float4*)&Bs[kk][tn * 8];
            float4 b1 = *(const float4*)&Bs[kk][tn * 8 + 4];
            b[0] = b0.x; b[1] = b0.y; b[2] = b0.z; b[3] = b0.w;
            b[4] = b1.x; b[5] = b1.y; b[6] = b1.z; b[7] = b1.w;
            #pragma unroll
            for (int r = 0; r < 8; ++r)
                #pragma unroll
                for (int c = 0; c < 8; ++c)
                    acc[r][c] = fmaf(a[r], b[c], acc[r][c]);
        }
        __syncthreads();
    }
    #pragma unroll
    for (int r = 0; r < 8; ++r) {
        int m = m0 + tm * 8 + r;
        if (m < N) {
            float4 o0 = make_float4(acc[r][0], acc[r][1], acc[r][2], acc[r][3]);
            float4 o1 = make_float4(acc[r][4], acc[r][5], acc[r][6], acc[r][7]);
            *(float4*)&out[(size_t)m * IN_SIZE + tn * 8]     = o0;
            *(float4*)&out[(size_t)m * IN_SIZE + tn * 8 + 4] = o1;
        }
    }
}

// ---------------- launch ----------------

extern "C" void kernel_launch(void* const* d_in, const int* in_sizes, int n_in,
                              void* d_out, int out_size, void* d_ws, size_t ws_size,
                              hipStream_t stream) {
    const float* h_in = (const float*)d_in[0];
    const float* ef   = (const float*)d_in[1];
    const int*   dst  = (const int*)d_in[2];
    const float* W    = (const float*)d_in[3];
    float* out = (float*)d_out;
    int N = in_sizes[0] / IN_SIZE;     // 50000
    int E = in_sizes[2];               // 1600000

    // workspace carve-out (256B aligned): ~13.4 MB total
    char* p = (char*)d_ws;
    auto take = [&](size_t bytes) { char* r = p; p += (bytes + 255) & ~(size_t)255; return r; };
    int*   deg     = (int*)take((size_t)N * 4);
    int*   cursor  = (int*)take((size_t)N * 4);
    int*   offsets = (int*)take((size_t)(N + 1) * 4);
    int nb = (N + 511) / 512;
    int*   bsum    = (int*)take((size_t)nb * 4);
    int*   bscan   = (int*)take((size_t)nb * 4);
    int*   eidsb   = (int*)take((size_t)E * 4);
    float* agg     = (float*)take((size_t)N * E_SIZE * 4);

    hipMemsetAsync(deg, 0, (size_t)N * 4, stream);
    k_hist    <<<(E + 255) / 256, 256, 0, stream>>>(dst, deg, E);
    k_blocksum<<<nb, 512, 0, stream>>>(deg, bsum, N);
    k_scanbsum<<<1, 64, 0, stream>>>(bsum, bscan, nb, offsets, N);
    k_offsets <<<nb, 512, 0, stream>>>(deg, bscan, offsets, cursor, N);
    k_fill    <<<(E + 255) / 256, 256, 0, stream>>>(dst, cursor, eidsb, E);
    k_node    <<<N, 64, 0, stream>>>(ef, offsets, eidsb, agg, N);
    k_gemm    <<<(N + 127) / 128, 256, 0, stream>>>(h_in, agg, W, out, N);
}

// Round 2
// 334.284 us; speedup vs baseline: 1.9937x; 1.9937x over previous
//
#include <hip/hip_runtime.h>
#include <math.h>

#define IN_SIZE 128
#define E_SIZE  32
#define KDIM    160
#define THRESH  0.5f

// ---------------- CSR construction ----------------

__global__ void k_hist(const int* __restrict__ dst, int* __restrict__ deg, int E) {
    int i = blockIdx.x * blockDim.x + threadIdx.x;
    if (i < E) atomicAdd(&deg[dst[i]], 1);
}

__global__ void k_blocksum(const int* __restrict__ deg, int* __restrict__ bsum, int N) {
    __shared__ int s[512];
    int i = blockIdx.x * 512 + threadIdx.x;
    s[threadIdx.x] = (i < N) ? deg[i] : 0;
    __syncthreads();
    for (int off = 256; off > 0; off >>= 1) {
        if (threadIdx.x < off) s[threadIdx.x] += s[threadIdx.x + off];
        __syncthreads();
    }
    if (threadIdx.x == 0) bsum[blockIdx.x] = s[0];
}

__global__ void k_scanbsum(const int* __restrict__ bsum, int* __restrict__ bscan,
                           int nb, int* __restrict__ offsets, int N) {
    if (blockIdx.x == 0 && threadIdx.x == 0) {
        int run = 0;
        for (int b = 0; b < nb; ++b) { bscan[b] = run; run += bsum[b]; }
        offsets[N] = run;   // == E
    }
}

__global__ void k_offsets(const int* __restrict__ deg, const int* __restrict__ bscan,
                          int* __restrict__ offsets, int* __restrict__ cursor, int N) {
    __shared__ int s[512];
    int tid = threadIdx.x;
    int i = blockIdx.x * 512 + tid;
    int v = (i < N) ? deg[i] : 0;
    s[tid] = v;
    __syncthreads();
    for (int off = 1; off < 512; off <<= 1) {       // Hillis-Steele inclusive scan
        int add = (tid >= off) ? s[tid - off] : 0;
        __syncthreads();
        s[tid] += add;
        __syncthreads();
    }
    if (i < N) {
        int o = bscan[blockIdx.x] + s[tid] - v;     // exclusive
        offsets[i] = o;
        cursor[i]  = o;
    }
}

__global__ void k_fill(const int* __restrict__ dst, int* __restrict__ cursor,
                       int* __restrict__ eids, int E) {
    int i = blockIdx.x * blockDim.x + threadIdx.x;
    if (i < E) {
        int p = atomicAdd(&cursor[dst[i]], 1);
        eids[p] = i;
    }
}

// ---------------- per-node aggregate (1 wave / node, 8 edges x 8 float4-lanes) ----------------
// lane = es*8 + q : es = edge slot (0..7), q = feature quarter (owns features q*4..q*4+3).

__device__ __forceinline__ float red_q(float x) {        // sum across q (lane bits 0..2)
    x += __shfl_xor(x, 1); x += __shfl_xor(x, 2); x += __shfl_xor(x, 4);
    return x;
}
__device__ __forceinline__ float red_es(float x) {       // sum across es (lane bits 3..5)
    x += __shfl_xor(x, 8); x += __shfl_xor(x, 16); x += __shfl_xor(x, 32);
    return x;
}
__device__ __forceinline__ float4 red_es4(float4 v) {
    v.x = red_es(v.x); v.y = red_es(v.y); v.z = red_es(v.z); v.w = red_es(v.w);
    return v;
}

__global__ __launch_bounds__(256, 8) void k_node(
    const float* __restrict__ ef, const int* __restrict__ offsets,
    const int* __restrict__ eids, float* __restrict__ agg, int N)
{
    int wid = blockIdx.x * (blockDim.x >> 6) + (threadIdx.x >> 6);   // node id
    if (wid >= N) return;
    int lane = threadIdx.x & 63;
    int es = lane >> 3;
    int q  = lane & 7;
    int start = offsets[wid];
    int deg   = offsets[wid + 1] - start;

    // phase A: per-feature sum over in-edges
    float4 esum = make_float4(0.f, 0.f, 0.f, 0.f);
    for (int i = es; i < deg; i += 8) {
        int eid = eids[start + i];
        float4 f = *(const float4*)&ef[(size_t)eid * E_SIZE + q * 4];
        esum.x += f.x; esum.y += f.y; esum.z += f.z; esum.w += f.w;
    }
    esum = red_es4(esum);
    float inv = (deg > 0) ? 1.f / (float)deg : 0.f;
    float4 hk = make_float4(esum.x * inv, esum.y * inv, esum.z * inv, esum.w * inv);
    float hn2 = hk.x * hk.x + hk.y * hk.y + hk.z * hk.z + hk.w * hk.w;
    hn2 = red_q(hn2);                                   // ||hk||^2, all lanes
    float hnorm = sqrtf(hn2);

    // phase B: cosine-thresholded masked sums (ef rows re-read; L2-hot)
    float4 ssum = make_float4(0.f, 0.f, 0.f, 0.f);
    float scnt = 0.f;
    for (int i = es; i < deg; i += 8) {
        int eid = eids[start + i];
        float4 f = *(const float4*)&ef[(size_t)eid * E_SIZE + q * 4];
        float num = hk.x * f.x + hk.y * f.y + hk.z * f.z + hk.w * f.w;
        float fn2 = f.x * f.x + f.y * f.y + f.z * f.z + f.w * f.w;
        num = red_q(num);
        fn2 = red_q(fn2);
        float cosv = num / (hnorm * sqrtf(fn2));        // NaN (0/0) -> excluded, matches jnp
        if (cosv < THRESH) {
            ssum.x += f.x; ssum.y += f.y; ssum.z += f.z; ssum.w += f.w;
            scnt += 1.f;
        }
    }
    ssum = red_es4(ssum);
    scnt = red_es(scnt);                                // each es-slot contributes once

    float4 a;
    if (scnt > 0.f) {
        float r = 1.f / scnt;
        a = make_float4(ssum.x * r, ssum.y * r, ssum.z * r, ssum.w * r);
    } else {
        a = hk;
    }
    if (es == 0) *(float4*)&agg[(size_t)wid * E_SIZE + q * 4] = a;
}

// ---------------- GEMM: out[N][128] = [h_in | agg] @ W^T ----------------
// BM=128, BN=128(all), BK=32; 256 threads; 8x8 acc per thread.

__global__ __launch_bounds__(256) void k_gemm(
    const float* __restrict__ A0,   // h_in [N][128]
    const float* __restrict__ A1,   // agg  [N][32]
    const float* __restrict__ W,    // [128][160]
    float* __restrict__ out, int N)
{
    __shared__ float As[128][33];   // +1 pad: a-reads conflict-free
    __shared__ float Bs[32][132];   // transposed W chunk; 132 keeps float4 rows 16B-aligned
    int t = threadIdx.x;
    int m0 = blockIdx.x * 128;
    int tn = t & 15, tm = t >> 4;
    float acc[8][8];
    #pragma unroll
    for (int r = 0; r < 8; ++r)
        #pragma unroll
        for (int c = 0; c < 8; ++c) acc[r][c] = 0.f;

    for (int chunk = 0; chunk < 5; ++chunk) {
        // stage A tile (rows m0..m0+127, k-cols chunk*32..+31)
        #pragma unroll
        for (int l = 0; l < 4; ++l) {
            int id = l * 256 + t;          // 0..1023 float4 slots
            int r = id >> 3;               // 0..127
            int qq = id & 7;               // float4 col within 32
            int m = m0 + r;
            float4 v = make_float4(0.f, 0.f, 0.f, 0.f);
            if (m < N) {
                if (chunk < 4) v = *(const float4*)&A0[(size_t)m * IN_SIZE + chunk * 32 + qq * 4];
                else           v = *(const float4*)&A1[(size_t)m * E_SIZE + qq * 4];
            }
            As[r][qq * 4 + 0] = v.x; As[r][qq * 4 + 1] = v.y;
            As[r][qq * 4 + 2] = v.z; As[r][qq * 4 + 3] = v.w;
        }
        // stage W chunk transposed: Bs[kk][h] = W[h][chunk*32+kk]
        {
            int h  = t >> 1;
            int kb = (t & 1) * 16;
            #pragma unroll
            for (int i2 = 0; i2 < 4; ++i2) {
                float4 v = *(const float4*)&W[(size_t)h * KDIM + chunk * 32 + kb + i2 * 4];
                int kkq = kb + i2 * 4;
                Bs[kkq + 0][h] = v.x; Bs[kkq + 1][h] = v.y;
                Bs[kkq + 2][h] = v.z; Bs[kkq + 3][h] = v.w;
            }
        }
        __syncthreads();
        #pragma unroll 4
        for (int kk = 0; kk < 32; ++kk) {
            float a[8], b[8];
            #pragma unroll
            for (int r = 0; r < 8; ++r) a[r] = As[tm * 8 + r][kk];
            float4 b0 = *(const float4*)&Bs[kk][tn * 8];
            float4 b1 = *(const float4*)&Bs[kk][tn * 8 + 4];
            b[0] = b0.x; b[1] = b0.y; b[2] = b0.z; b[3] = b0.w;
            b[4] = b1.x; b[5] = b1.y; b[6] = b1.z; b[7] = b1.w;
            #pragma unroll
            for (int r = 0; r < 8; ++r)
                #pragma unroll
                for (int c = 0; c < 8; ++c)
                    acc[r][c] = fmaf(a[r], b[c], acc[r][c]);
        }
        __syncthreads();
    }
    #pragma unroll
    for (int r = 0; r < 8; ++r) {
        int m = m0 + tm * 8 + r;
        if (m < N) {
            float4 o0 = make_float4(acc[r][0], acc[r][1], acc[r][2], acc[r][3]);
            float4 o1 = make_float4(acc[r][4], acc[r][5], acc[r][6], acc[r][7]);
            *(float4*)&out[(size_t)m * IN_SIZE + tn * 8]     = o0;
            *(float4*)&out[(size_t)m * IN_SIZE + tn * 8 + 4] = o1;
        }
    }
}

// ---------------- launch ----------------

extern "C" void kernel_launch(void* const* d_in, const int* in_sizes, int n_in,
                              void* d_out, int out_size, void* d_ws, size_t ws_size,
                              hipStream_t stream) {
    const float* h_in = (const float*)d_in[0];
    const float* ef   = (const float*)d_in[1];
    const int*   dst  = (const int*)d_in[2];
    const float* W    = (const float*)d_in[3];
    float* out = (float*)d_out;
    int N = in_sizes[0] / IN_SIZE;     // 50000
    int E = in_sizes[2];               // 1600000

    // workspace carve-out (256B aligned)
    char* p = (char*)d_ws;
    auto take = [&](size_t bytes) { char* r = p; p += (bytes + 255) & ~(size_t)255; return r; };
    int*   deg     = (int*)take((size_t)N * 4);
    int*   cursor  = (int*)take((size_t)N * 4);
    int*   offsets = (int*)take((size_t)(N + 1) * 4);
    int nb = (N + 511) / 512;
    int*   bsum    = (int*)take((size_t)nb * 4);
    int*   bscan   = (int*)take((size_t)nb * 4);
    int*   eidsb   = (int*)take((size_t)E * 4);
    float* agg     = (float*)take((size_t)N * E_SIZE * 4);

    hipMemsetAsync(deg, 0, (size_t)N * 4, stream);
    k_hist    <<<(E + 255) / 256, 256, 0, stream>>>(dst, deg, E);
    k_blocksum<<<nb, 512, 0, stream>>>(deg, bsum, N);
    k_scanbsum<<<1, 64, 0, stream>>>(bsum, bscan, nb, offsets, N);
    k_offsets <<<nb, 512, 0, stream>>>(deg, bscan, offsets, cursor, N);
    k_fill    <<<(E + 255) / 256, 256, 0, stream>>>(dst, cursor, eidsb, E);
    k_node    <<<(N + 3) / 4, 256, 0, stream>>>(ef, offsets, eidsb, agg, N);
    k_gemm    <<<(N + 127) / 128, 256, 0, stream>>>(h_in, agg, W, out, N);
}